// Round 10
// baseline (3195.178 us; speedup 1.0000x reference)
//
#include <hip/hip_runtime.h>

#define TSEQ 512

typedef unsigned short us8v __attribute__((ext_vector_type(8)));
typedef __bf16 bf16x8 __attribute__((ext_vector_type(8)));
typedef float f32x4 __attribute__((ext_vector_type(4)));
typedef unsigned u32x4 __attribute__((ext_vector_type(4)));

// ---- workspace layout (bytes) ----
#define OFF_BIAS  0u           // 2*2048 f32
#define OFF_X16   16384u       // x bf16 [512 t][64 b][64 d] = 4 MiB
#define OFF_W0    4210688u     // Wcat0 bf16 [2048][576]
#define OFF_W1    6569984u     // Wcat1 bf16 [2048][1024]
#define OFF_Y0P   10764288u    // y0 bf16 [512 t][4 bg][16 hg][16 b][32 p] = 32 MiB
#define OFF_RING1 44318720u    // h1 ring bf16 [2 par][4 bg][16 hg][16 b][32 p] = 128 KiB
#define OFF_FLAGS 44449792u    // [4 bg][16 hg] epoch u32 @ 128B = 8 KiB

static __device__ __forceinline__ unsigned short f2bf(float f) {
    unsigned u = __builtin_bit_cast(unsigned, f);
    u += 0x7fffu + ((u >> 16) & 1u);            // RNE
    return (unsigned short)(u >> 16);
}
static __device__ __forceinline__ float sigmf(float x) { return 1.0f / (1.0f + __expf(-x)); }
static __device__ __forceinline__ float tanh_fast(float x) {
    float a = fabsf(x);
    float e = __expf(-2.0f * a);
    float t = (1.0f - e) / (1.0f + e);
    return copysignf(t, x);
}
static __device__ __forceinline__ f32x4 mfma16(us8v a, us8v b, f32x4 c) {
    return __builtin_amdgcn_mfma_f32_16x16x32_bf16(
        __builtin_bit_cast(bf16x8, a), __builtin_bit_cast(bf16x8, b), c, 0, 0, 0);
}
static __device__ __forceinline__ us8v asb(u32x4 v) { return __builtin_bit_cast(us8v, v); }

// ---------------- setup: fp32 -> bf16 conversions + concatenated weights ----------------
__global__ void setup_kernel(const float* __restrict__ x,
                             const float* __restrict__ wih0, const float* __restrict__ whh0,
                             const float* __restrict__ bih0, const float* __restrict__ bhh0,
                             const float* __restrict__ wih1, const float* __restrict__ whh1,
                             const float* __restrict__ bih1, const float* __restrict__ bhh1,
                             char* __restrict__ ws)
{
    unsigned idx = blockIdx.x * blockDim.x + threadIdx.x;
    unsigned stride = gridDim.x * blockDim.x;
    unsigned short* x16 = (unsigned short*)(ws + OFF_X16);
    unsigned short* w0  = (unsigned short*)(ws + OFF_W0);
    unsigned short* w1  = (unsigned short*)(ws + OFF_W1);
    float* bias = (float*)(ws + OFF_BIAS);
    const unsigned NX  = 64u*512u*64u;
    const unsigned NW0 = 2048u*576u;
    const unsigned NW1 = 2048u*1024u;
    const unsigned NT  = NX + NW0 + NW1 + 4096u;
    for (unsigned i = idx; i < NT; i += stride) {
        if (i < NX) {
            unsigned d = i & 63u, b = (i >> 6) & 63u, t = i >> 12;
            x16[i] = f2bf(x[((b << 9) + t) * 64u + d]);
        } else if (i < NX + NW0) {
            unsigned k = i - NX; unsigned r = k / 576u, c = k % 576u;
            float v = (c < 64u) ? wih0[r*64u + c] : whh0[r*512u + (c - 64u)];
            w0[k] = f2bf(v);
        } else if (i < NX + NW0 + NW1) {
            unsigned k = i - NX - NW0; unsigned r = k >> 10, c = k & 1023u;
            float v = (c < 512u) ? wih1[(r<<9) + c] : whh1[(r<<9) + (c - 512u)];
            w1[k] = f2bf(v);
        } else {
            unsigned k = i - NX - NW0 - NW1;
            float v = (k < 2048u) ? (bih0[k] + bhh0[k]) : (bih1[k-2048u] + bhh1[k-2048u]);
            bias[k] = v;
        }
    }
}

// ---------------- persistent recurrence kernel ----------------
// 64 blocks = 4 bg x 16 hg; block owns 32 h (128 gate rows), A-frags in regs.
// r6 protocol: monotone per-block epoch flag @128B, 2-deep in-asm ping-pong
// poll (pre-loads retired inside the same asm -> no in-flight reg hazard),
// plain-cached write-once payload reads, sc0sc1 ring reads, one barrier/step
// + per-wave ack + LDS wave-counter flag release.
__launch_bounds__(256, 1)
__global__ void lstm_persist(char* __restrict__ ws)
{
    const int tid  = threadIdx.x;
    const int kq   = tid >> 6;      // wave = K-quarter
    const int lane = tid & 63;
    const int l15  = lane & 15;     // B-frag batch row / D col
    const int lhi  = lane >> 4;     // k-sub / D row-group
    const int bg   = blockIdx.x & 3;
    const int hg   = blockIdx.x >> 2;   // 0..15

    const float* bias = (const float*)(ws + OFF_BIAS);
    const char*  x16  = ws + OFF_X16;
    char* y0p   = ws + OFF_Y0P;
    char* ring1 = ws + OFF_RING1;
    char* flags = ws + OFF_FLAGS;

    __shared__ __align__(16) char arena[86016];     // >80KB -> 1 block/CU
    float* gsum   = (float*)arena;                  // [2 par][128 rows][69] = 70656 B
    float* bias_l = (float*)(arena + 70656);        // 128 f32
    unsigned* wcnt = (unsigned*)(arena + 71680);    // [2]

    if (tid == 0) { wcnt[0] = 0u; wcnt[1] = 0u; }
    if (tid < 128) bias_l[tid] = bias[(tid >> 5)*512 + hg*32 + (tid & 31)];

    // cell state: thread owns (b_ = tid>>4, p = p0, p0+1)
    const int b_ = tid >> 4, p0 = (tid & 15) * 2;
    float cs0 = 0.0f, cs1 = 0.0f;

    // A fragments: A[m][kk]; m = 8 M-tiles (gate*2+half), kk = wave-local k-tile
    us8v A[8][8];
    {
        const char* w0p = ws + OFF_W0;
        #pragma unroll
        for (int m = 0; m < 8; ++m) {
            const char* base = w0p
                + (size_t)((m >> 1)*512 + hg*32 + (m & 1)*16 + l15)*1152 + lhi*16;
            #pragma unroll
            for (int kk = 0; kk < 4; ++kk)
                A[m][kk] = *(const us8v*)(base + (2 + kq*4 + kk)*64);   // h k-tiles
            if (kq < 2) A[m][4] = *(const us8v*)(base + kq*64);         // x k-tiles
        }
    }
    __syncthreads();

    const int vo_h = kq*4096 + l15*64 + lhi*16;                 // frag offset in 16KB slice
    const int vo_x = (bg*16 + l15)*128 + (kq & 1)*64 + lhi*16;  // frag offset in x16[t]
    const char* fp = flags + bg*2048 + (lane & 15)*128;         // poll slot (16 slots)
    const char* fq = flags + bg*2048 + hg*128;                  // own slot

    u32x4 xr, yr0, yr1, yr2, yr3, h0, h1, h2, h3;

// poll (layer 0): x pre-load + 2-deep flag ping-pong, all in ONE asm
#define POLL_L0(SBX, EP)                                                        \
    do { unsigned pf0_, pf1_, ep_ = (EP);                                       \
    asm volatile(                                                               \
        "global_load_dwordx4 %0, %3, %4\n\t"                                    \
        "global_load_dword %1, %5, off sc0 sc1\n\t"                             \
        "global_load_dword %2, %5, off sc0 sc1\n\t"                             \
        "1:\n\t"                                                                \
        "s_waitcnt vmcnt(1)\n\t"                                                \
        "v_cmp_lt_u32 vcc, %1, %6\n\t"                                          \
        "s_cbranch_vccz 2f\n\t"                                                 \
        "global_load_dword %1, %5, off sc0 sc1\n\t"                             \
        "s_waitcnt vmcnt(1)\n\t"                                                \
        "v_cmp_lt_u32 vcc, %2, %6\n\t"                                          \
        "s_cbranch_vccz 2f\n\t"                                                 \
        "global_load_dword %2, %5, off sc0 sc1\n\t"                             \
        "s_branch 1b\n\t"                                                       \
        "2:\n\t"                                                                \
        "s_waitcnt vmcnt(0)"                                                    \
        : "=&v"(xr), "=&v"(pf0_), "=&v"(pf1_)                                   \
        : "v"(vo_x), "s"(SBX), "v"(fp), "v"(ep_)                                \
        : "vcc", "memory"); } while (0)

// poll (layer 1): 4 y0 pre-loads + flag ping-pong, one asm
#define POLL_L1(SBY, EP)                                                        \
    do { unsigned pf0_, pf1_, ep_ = (EP);                                       \
    asm volatile(                                                               \
        "global_load_dwordx4 %0, %6, %7\n\t"                                    \
        "global_load_dwordx4 %1, %6, %7 offset:1024\n\t"                        \
        "global_load_dwordx4 %2, %6, %7 offset:2048\n\t"                        \
        "global_load_dwordx4 %3, %6, %7 offset:3072\n\t"                        \
        "global_load_dword %4, %8, off sc0 sc1\n\t"                             \
        "global_load_dword %5, %8, off sc0 sc1\n\t"                             \
        "1:\n\t"                                                                \
        "s_waitcnt vmcnt(1)\n\t"                                                \
        "v_cmp_lt_u32 vcc, %4, %9\n\t"                                          \
        "s_cbranch_vccz 2f\n\t"                                                 \
        "global_load_dword %4, %8, off sc0 sc1\n\t"                             \
        "s_waitcnt vmcnt(1)\n\t"                                                \
        "v_cmp_lt_u32 vcc, %5, %9\n\t"                                          \
        "s_cbranch_vccz 2f\n\t"                                                 \
        "global_load_dword %5, %8, off sc0 sc1\n\t"                             \
        "s_branch 1b\n\t"                                                       \
        "2:\n\t"                                                                \
        "s_waitcnt vmcnt(0)"                                                    \
        : "=&v"(yr0), "=&v"(yr1), "=&v"(yr2), "=&v"(yr3), "=&v"(pf0_), "=&v"(pf1_) \
        : "v"(vo_h), "s"(SBY), "v"(fp), "v"(ep_)                                \
        : "vcc", "memory"); } while (0)

// payload loads (self-contained): plain cached / cache-bypass variants
#define LOADH4(SB)                                                              \
    asm volatile(                                                               \
        "global_load_dwordx4 %0, %4, %5\n\t"                                    \
        "global_load_dwordx4 %1, %4, %5 offset:1024\n\t"                        \
        "global_load_dwordx4 %2, %4, %5 offset:2048\n\t"                        \
        "global_load_dwordx4 %3, %4, %5 offset:3072\n\t"                        \
        "s_waitcnt vmcnt(0)"                                                    \
        : "=&v"(h0),"=&v"(h1),"=&v"(h2),"=&v"(h3)                               \
        : "v"(vo_h), "s"(SB) : "memory")
#define LOADR4(SB)                                                              \
    asm volatile(                                                               \
        "global_load_dwordx4 %0, %4, %5 sc0 sc1\n\t"                            \
        "global_load_dwordx4 %1, %4, %5 offset:1024 sc0 sc1\n\t"                \
        "global_load_dwordx4 %2, %4, %5 offset:2048 sc0 sc1\n\t"                \
        "global_load_dwordx4 %3, %4, %5 offset:3072 sc0 sc1\n\t"                \
        "s_waitcnt vmcnt(0)"                                                    \
        : "=&v"(h0),"=&v"(h1),"=&v"(h2),"=&v"(h3)                               \
        : "v"(vo_h), "s"(SB) : "memory")

#define GSUM_WRITE(PAR)                                                         \
    do { float* gs_ = gsum + (PAR)*8832;                                        \
        _Pragma("unroll")                                                       \
        for (int m = 0; m < 8; ++m) {                                           \
            _Pragma("unroll")                                                   \
            for (int q = 0; q < 4; ++q)                                         \
                gs_[(m*16 + lhi*4 + q)*69 + kq*17 + l15] = acc[m][q];           \
        } } while (0)

#define ACT_STEP(PAR, EPS, SBSL)                                                \
    do {                                                                        \
        const float* gsr = gsum + (PAR)*8832;                                   \
        float g4a[4], g4b[4];                                                   \
        _Pragma("unroll")                                                       \
        for (int g = 0; g < 4; ++g) {                                           \
            float sa = bias_l[g*32 + p0], sb2 = bias_l[g*32 + p0 + 1];          \
            _Pragma("unroll")                                                   \
            for (int kk = 0; kk < 4; ++kk) {                                    \
                sa  += gsr[(g*32 + p0)*69     + kk*17 + b_];                    \
                sb2 += gsr[(g*32 + p0 + 1)*69 + kk*17 + b_];                    \
            }                                                                   \
            g4a[g] = sa; g4b[g] = sb2;                                          \
        }                                                                       \
        float iv = sigmf(g4a[0]), fv = sigmf(g4a[1]);                           \
        float gv = tanh_fast(g4a[2]), ov = sigmf(g4a[3]);                       \
        cs0 = fv*cs0 + iv*gv;                                                   \
        float ha = ov * tanh_fast(cs0);                                         \
        iv = sigmf(g4b[0]); fv = sigmf(g4b[1]);                                 \
        gv = tanh_fast(g4b[2]); ov = sigmf(g4b[3]);                             \
        cs1 = fv*cs1 + iv*gv;                                                   \
        float hb = ov * tanh_fast(cs1);                                         \
        unsigned pk = ((unsigned)f2bf(ha)) | (((unsigned)f2bf(hb)) << 16);      \
        const char* dst_ = (SBSL) + b_*64 + p0*2;                               \
        asm volatile("global_store_dword %0, %1, off sc0 sc1"                   \
                     :: "v"(dst_), "v"(pk) : "memory");                         \
        asm volatile("s_waitcnt vmcnt(0)" ::: "memory");                        \
        if (lane == 0) {                                                        \
            unsigned prev_ = __hip_atomic_fetch_add(&wcnt[PAR], 1u,             \
                                __ATOMIC_RELAXED, __HIP_MEMORY_SCOPE_WORKGROUP);\
            if (prev_ == 3u) {                                                  \
                __hip_atomic_store(&wcnt[PAR], 0u,                              \
                                __ATOMIC_RELAXED, __HIP_MEMORY_SCOPE_WORKGROUP);\
                unsigned ep_ = (EPS);                                           \
                asm volatile("global_store_dword %0, %1, off sc0 sc1"           \
                             :: "v"(fq), "v"(ep_) : "memory");                  \
            }                                                                   \
        }                                                                       \
    } while (0)

    // ================= layer 0 : K = 576 = [x_t(64) | h0(512)] =================
    for (int t = 0; t < TSEQ; ++t) {
        const int par = t & 1;
        const char* sbx = x16 + (size_t)t*8192;
        f32x4 acc[8] = {{0.f,0.f,0.f,0.f},{0.f,0.f,0.f,0.f},{0.f,0.f,0.f,0.f},{0.f,0.f,0.f,0.f},
                        {0.f,0.f,0.f,0.f},{0.f,0.f,0.f,0.f},{0.f,0.f,0.f,0.f},{0.f,0.f,0.f,0.f}};
        if (t > 0) {
            POLL_L0(sbx, (unsigned)t);
            LOADH4(y0p + ((size_t)(t-1)*4 + bg)*16384);   // plain: write-once, flag-ordered
            if (kq < 2) {
                #pragma unroll
                for (int m = 0; m < 8; ++m) acc[m] = mfma16(A[m][4], asb(xr), acc[m]);
            }
            #pragma unroll
            for (int m = 0; m < 8; ++m) acc[m] = mfma16(A[m][0], asb(h0), acc[m]);
            #pragma unroll
            for (int m = 0; m < 8; ++m) acc[m] = mfma16(A[m][1], asb(h1), acc[m]);
            #pragma unroll
            for (int m = 0; m < 8; ++m) acc[m] = mfma16(A[m][2], asb(h2), acc[m]);
            #pragma unroll
            for (int m = 0; m < 8; ++m) acc[m] = mfma16(A[m][3], asb(h3), acc[m]);
        } else {
            asm volatile("global_load_dwordx4 %0, %1, %2\n\ts_waitcnt vmcnt(0)"
                         : "=&v"(xr) : "v"(vo_x), "s"(sbx) : "memory");
            if (kq < 2) {
                #pragma unroll
                for (int m = 0; m < 8; ++m) acc[m] = mfma16(A[m][4], asb(xr), acc[m]);
            }
        }
        GSUM_WRITE(par);
        __syncthreads();
        ACT_STEP(par, (unsigned)(t + 1), y0p + ((size_t)t*4 + bg)*16384 + hg*1024);
    }

    __syncthreads();
    {   // ---- reload A + bias for layer 1 (K = 1024 = [y0(512) | h1(512)]) ----
        const char* w1p = ws + OFF_W1;
        #pragma unroll
        for (int m = 0; m < 8; ++m) {
            const char* base = w1p
                + (size_t)((m >> 1)*512 + hg*32 + (m & 1)*16 + l15)*2048 + lhi*16;
            #pragma unroll
            for (int kk = 0; kk < 4; ++kk) {
                A[m][kk]     = *(const us8v*)(base + (kq*4 + kk)*64);        // y0 k-tiles
                A[m][kk + 4] = *(const us8v*)(base + (16 + kq*4 + kk)*64);   // h  k-tiles
            }
        }
    }
    if (tid < 128) bias_l[tid] = bias[2048 + (tid >> 5)*512 + hg*32 + (tid & 31)];
    __syncthreads();
    // cs0/cs1 carry over: layer1 initial c = layer0 final c (reference quirk)

    for (int t = 0; t < TSEQ; ++t) {
        const int par = t & 1;
        const char* sby = y0p + ((size_t)t*4 + bg)*16384;
        POLL_L1(sby, (unsigned)(512 + t));
        if (t == 0) { LOADR4(y0p + ((size_t)511*4 + bg)*16384); }               // h1_init = h0_final
        else        { LOADR4(ring1 + ((size_t)((t-1) & 1)*4 + bg)*16384); }     // ring: bypass

        f32x4 acc[8] = {{0.f,0.f,0.f,0.f},{0.f,0.f,0.f,0.f},{0.f,0.f,0.f,0.f},{0.f,0.f,0.f,0.f},
                        {0.f,0.f,0.f,0.f},{0.f,0.f,0.f,0.f},{0.f,0.f,0.f,0.f},{0.f,0.f,0.f,0.f}};
        #pragma unroll
        for (int m = 0; m < 8; ++m) acc[m] = mfma16(A[m][0], asb(yr0), acc[m]);
        #pragma unroll
        for (int m = 0; m < 8; ++m) acc[m] = mfma16(A[m][1], asb(yr1), acc[m]);
        #pragma unroll
        for (int m = 0; m < 8; ++m) acc[m] = mfma16(A[m][2], asb(yr2), acc[m]);
        #pragma unroll
        for (int m = 0; m < 8; ++m) acc[m] = mfma16(A[m][3], asb(yr3), acc[m]);
        #pragma unroll
        for (int m = 0; m < 8; ++m) acc[m] = mfma16(A[m][4], asb(h0), acc[m]);
        #pragma unroll
        for (int m = 0; m < 8; ++m) acc[m] = mfma16(A[m][5], asb(h1), acc[m]);
        #pragma unroll
        for (int m = 0; m < 8; ++m) acc[m] = mfma16(A[m][6], asb(h2), acc[m]);
        #pragma unroll
        for (int m = 0; m < 8; ++m) acc[m] = mfma16(A[m][7], asb(h3), acc[m]);

        GSUM_WRITE(par);
        __syncthreads();
        ACT_STEP(par, (unsigned)(513 + t), ring1 + ((size_t)par*4 + bg)*16384 + hg*1024);
    }
#undef POLL_L0
#undef POLL_L1
#undef LOADH4
#undef LOADR4
#undef GSUM_WRITE
#undef ACT_STEP
}

// ---------------- final projection: out = h1_final @ lin_w.T + lin_b ----------------
__global__ void final_linear(const char* __restrict__ ws,
                             const float* __restrict__ linw, const float* __restrict__ linb,
                             float* __restrict__ out)
{
    __shared__ float hrow[512];
    int b = blockIdx.x;        // global batch 0..63
    int o = threadIdx.x;       // 64 outputs
    int bg = b >> 4, bl = b & 15;
    // t=511 -> ring parity 1; layout [par][bg][hg][16 b][32 p]
    const char* src = ws + OFF_RING1 + ((size_t)(4 + bg))*16384
                         + (o >> 2)*1024 + bl*64 + (o & 3)*16;
    {
        us8v v = *(const us8v*)src;
        #pragma unroll
        for (int p = 0; p < 8; ++p)
            hrow[o*8+p] = __builtin_bit_cast(float, ((unsigned)v[p]) << 16);
    }
    __syncthreads();
    float acc = linb[o];
    const float* wrow = linw + o*512;
    #pragma unroll 8
    for (int k = 0; k < 512; ++k) acc += hrow[k] * wrow[k];
    out[b*64 + o] = acc;
}

extern "C" void kernel_launch(void* const* d_in, const int* in_sizes, int n_in,
                              void* d_out, int out_size, void* d_ws, size_t ws_size,
                              hipStream_t stream)
{
    const float* x    = (const float*)d_in[0];
    const float* wih0 = (const float*)d_in[1];
    const float* whh0 = (const float*)d_in[2];
    const float* bih0 = (const float*)d_in[3];
    const float* bhh0 = (const float*)d_in[4];
    const float* wih1 = (const float*)d_in[5];
    const float* whh1 = (const float*)d_in[6];
    const float* bih1 = (const float*)d_in[7];
    const float* bhh1 = (const float*)d_in[8];
    const float* linw = (const float*)d_in[9];
    const float* linb = (const float*)d_in[10];
    char* ws = (char*)d_ws;

    // zero epoch flags each call (flags are the only cross-call-sensitive state)
    (void)hipMemsetAsync(ws + OFF_FLAGS, 0, 8192, stream);
    hipLaunchKernelGGL(setup_kernel, dim3(1024), dim3(256), 0, stream,
                       x, wih0, whh0, bih0, bhh0, wih1, whh1, bih1, bhh1, ws);
    hipLaunchKernelGGL(lstm_persist, dim3(64), dim3(256), 0, stream, ws);
    hipLaunchKernelGGL(final_linear, dim3(64), dim3(64), 0, stream,
                       ws, linw, linb, (float*)d_out);
}

// Round 11
// 2330.405 us; speedup vs baseline: 1.3711x; 1.3711x over previous
//
#include <hip/hip_runtime.h>

#define TSEQ 512

typedef unsigned short us8v __attribute__((ext_vector_type(8)));
typedef __bf16 bf16x8 __attribute__((ext_vector_type(8)));
typedef float f32x4 __attribute__((ext_vector_type(4)));
typedef unsigned u32x4 __attribute__((ext_vector_type(4)));

// ---- workspace layout (bytes) ----
#define OFF_FLAGS 0u           // [4 bg][32 hg] epoch u32 @ 128B stride = 16 KiB
#define OFF_BIAS  16384u       // 2*2048 f32
#define OFF_X16   32768u       // x bf16 [512 t][64 b][64 d] = 4 MiB
#define OFF_W0    4227072u     // Wcat0 bf16 [2048][576]
#define OFF_W1    6586368u     // Wcat1 bf16 [2048][1024]
#define OFF_Y0    10780672u    // y0 xch bf16 [512 t][4 bg][32 hg][16 b][16 p] = 32 MiB
#define OFF_RING  44335104u    // h1 ring bf16 [2 par][4 bg][32 hg][16 b][16 p] = 128 KiB

static __device__ __forceinline__ unsigned short f2bf(float f) {
    unsigned u = __builtin_bit_cast(unsigned, f);
    u += 0x7fffu + ((u >> 16) & 1u);            // RNE
    return (unsigned short)(u >> 16);
}
static __device__ __forceinline__ float sigmf(float x) { return 1.0f / (1.0f + __expf(-x)); }
static __device__ __forceinline__ float tanh_fast(float x) {
    float a = fabsf(x);
    float e = __expf(-2.0f * a);
    float t = (1.0f - e) / (1.0f + e);
    return copysignf(t, x);
}
static __device__ __forceinline__ f32x4 mfma16(us8v a, us8v b, f32x4 c) {
    return __builtin_amdgcn_mfma_f32_16x16x32_bf16(
        __builtin_bit_cast(bf16x8, a), __builtin_bit_cast(bf16x8, b), c, 0, 0, 0);
}
static __device__ __forceinline__ us8v asb(u32x4 v) { return __builtin_bit_cast(us8v, v); }

// ---------------- setup: fp32 -> bf16 conversions + concatenated weights ----------------
__global__ void setup_kernel(const float* __restrict__ x,
                             const float* __restrict__ wih0, const float* __restrict__ whh0,
                             const float* __restrict__ bih0, const float* __restrict__ bhh0,
                             const float* __restrict__ wih1, const float* __restrict__ whh1,
                             const float* __restrict__ bih1, const float* __restrict__ bhh1,
                             char* __restrict__ ws)
{
    unsigned idx = blockIdx.x * blockDim.x + threadIdx.x;
    unsigned stride = gridDim.x * blockDim.x;
    unsigned short* x16 = (unsigned short*)(ws + OFF_X16);
    unsigned short* w0  = (unsigned short*)(ws + OFF_W0);
    unsigned short* w1  = (unsigned short*)(ws + OFF_W1);
    float* bias = (float*)(ws + OFF_BIAS);
    const unsigned NX  = 64u*512u*64u;      // 2097152
    const unsigned NW0 = 2048u*576u;        // 1179648
    const unsigned NW1 = 2048u*1024u;       // 2097152
    const unsigned NT  = NX + NW0 + NW1 + 4096u;
    for (unsigned i = idx; i < NT; i += stride) {
        if (i < NX) {
            // transpose to [t][b][d]
            unsigned d = i & 63u, b = (i >> 6) & 63u, t = i >> 12;
            x16[i] = f2bf(x[((b << 9) + t) * 64u + d]);
        } else if (i < NX + NW0) {
            unsigned k = i - NX; unsigned r = k / 576u, c = k % 576u;
            float v = (c < 64u) ? wih0[r*64u + c] : whh0[r*512u + (c - 64u)];
            w0[k] = f2bf(v);
        } else if (i < NX + NW0 + NW1) {
            unsigned k = i - NX - NW0; unsigned r = k >> 10, c = k & 1023u;
            float v = (c < 512u) ? wih1[(r<<9) + c] : whh1[(r<<9) + (c - 512u)];
            w1[k] = f2bf(v);
        } else {
            unsigned k = i - NX - NW0 - NW1;   // 0..4095
            float v = (k < 2048u) ? (bih0[k] + bhh0[k]) : (bih1[k-2048u] + bhh1[k-2048u]);
            bias[k] = v;
        }
    }
}

// ---------------- persistent recurrence kernel ----------------
// 128 blocks = 4 bg x 32 hg. Monotone epoch flag per block (128B-spread),
// 2-deep pipelined poll, block-major 512B payload (one 128B line per wave),
// one barrier per step + per-wave ack + LDS wave-counter flag release.
// ALL global loads inside the loops are inline asm (stale-poll-safe waits).
__launch_bounds__(256, 1)
__global__ void lstm_persist(char* __restrict__ ws)
{
    const int tid  = threadIdx.x;
    const int kq   = tid >> 6;      // wave = K-quarter
    const int lane = tid & 63;
    const int l15  = lane & 15;     // B-frag batch row / D col
    const int lhi  = lane >> 4;     // k-sub / D row-group
    const int bg   = blockIdx.x & 3;
    const int hg   = blockIdx.x >> 2;

    const float* bias = (const float*)(ws + OFF_BIAS);
    const char*  x16  = ws + OFF_X16;
    char* y0   = ws + OFF_Y0;
    char* ring = ws + OFF_RING;
    const char* flagbase = ws + OFF_FLAGS + bg*4096;   // 32 slots @128B
    const char* fq       = flagbase + hg*128;          // our slot

    __shared__ __align__(16) char arena[86016];        // >80KB -> 1 block/CU
    float* gsum       = (float*)arena;                 // [2 par][64 rows][4*17] = 34816 B
    float* bias_l     = (float*)(arena + 34816);       // 64 f32
    unsigned* wcnt    = (unsigned*)(arena + 35072);    // [2] wave-done counters

    if (tid == 0) { wcnt[0] = 0u; wcnt[1] = 0u; }
    if (tid < 64) bias_l[tid] = bias[(tid >> 4)*512 + hg*16 + (tid & 15)];

    float cst = 0.0f;   // cell state: thread owns (b = tid&63... -> b_ = tid>>4, p_ = tid&15)

    // A fragments: A[m][kk], m = gate, kk = local k-tile of this wave
    us8v A[4][8];
    {
        const char* w0p = ws + OFF_W0;
        #pragma unroll
        for (int m = 0; m < 4; ++m) {
            const char* base = w0p + (size_t)(m*512 + hg*16 + l15)*1152 + lhi*16;
            #pragma unroll
            for (int kk = 0; kk < 4; ++kk)
                A[m][kk] = *(const us8v*)(base + (2 + kq*4 + kk)*64);   // h k-tiles
            if (kq < 2) A[m][4] = *(const us8v*)(base + kq*64);         // x k-tiles
        }
    }
    __syncthreads();

    // lane's fragment byte offset inside a [32 hg][16 b][16 p] (16KB) xch slot:
    // k-tile kt (32 k) -> hg' = kt*2 + (lhi>>1); addr = hg'*512 + l15*32 + (lhi&1)*16
    const int base_off = kq*4096 + (lhi >> 1)*512 + l15*32 + (lhi & 1)*16;   // kk stride 1024

    unsigned pf0 = 0, pf1 = 0;   // poll ping-pong regs (live across straggler window)

#define POLL(EP) do {                                                            \
        unsigned ep_ = (EP);                                                     \
        const char* fp_ = flagbase + ((lane & 31) << 7);                         \
        asm volatile(                                                            \
            "global_load_dword %0, %2, off sc0 sc1\n\t"                          \
            "global_load_dword %1, %2, off sc0 sc1\n\t"                          \
            "1:\n\t"                                                             \
            "s_waitcnt vmcnt(1)\n\t"                                             \
            "v_cmp_lt_u32 vcc, %0, %3\n\t"                                       \
            "s_cbranch_vccz 2f\n\t"                                              \
            "global_load_dword %0, %2, off sc0 sc1\n\t"                          \
            "s_waitcnt vmcnt(1)\n\t"                                             \
            "v_cmp_lt_u32 vcc, %1, %3\n\t"                                       \
            "s_cbranch_vccz 2f\n\t"                                              \
            "global_load_dword %1, %2, off sc0 sc1\n\t"                          \
            "s_branch 1b\n\t"                                                    \
            "2:\n\t"                                                             \
            : "+v"(pf0), "+v"(pf1) : "v"(fp_), "s"(ep_) : "vcc", "memory");      \
    } while (0)

#define GSUM_WRITE(PAR) do {                                                     \
        float* gs_ = gsum + (PAR)*4352;                                          \
        _Pragma("unroll")                                                        \
        for (int m = 0; m < 4; ++m) {                                            \
            _Pragma("unroll")                                                    \
            for (int q = 0; q < 4; ++q)                                          \
                gs_[(m*16 + lhi*4 + q)*68 + kq*17 + l15] = acc[m][q];            \
        }                                                                        \
    } while (0)

#define ACT_TAIL(SLICE, EPOCH, PAR) do {                                         \
        int b_ = tid >> 4, p_ = tid & 15;                                        \
        const float* gsr_ = gsum + (PAR)*4352;                                   \
        float g4_[4];                                                            \
        _Pragma("unroll")                                                        \
        for (int g = 0; g < 4; ++g) {                                            \
            float s_ = bias_l[g*16 + p_];                                        \
            _Pragma("unroll")                                                    \
            for (int kk = 0; kk < 4; ++kk) s_ += gsr_[(g*16 + p_)*68 + kk*17 + b_]; \
            g4_[g] = s_;                                                         \
        }                                                                        \
        float iv_ = sigmf(g4_[0]), fv_ = sigmf(g4_[1]);                          \
        float gv_ = tanh_fast(g4_[2]), ov_ = sigmf(g4_[3]);                      \
        cst = fv_*cst + iv_*gv_;                                                 \
        float h_ = ov_ * tanh_fast(cst);                                         \
        unsigned hv_ = f2bf(h_);                                                 \
        unsigned pk_ = (hv_ & 0xffffu) | (((unsigned)__shfl_xor((int)hv_, 1)) << 16); \
        if (!(p_ & 1)) {                                                         \
            const char* dst_ = (SLICE) + b_*32 + p_*2;                           \
            asm volatile("global_store_dword %0, %1, off sc0 sc1"                \
                         :: "v"(dst_), "v"(pk_) : "memory");                     \
        }                                                                        \
        asm volatile("s_waitcnt vmcnt(0)" ::: "memory");                         \
        if (lane == 0) {                                                         \
            unsigned prev_ = __hip_atomic_fetch_add(&wcnt[PAR], 1u,              \
                                __ATOMIC_RELAXED, __HIP_MEMORY_SCOPE_WORKGROUP); \
            if (prev_ == 3u) {                                                   \
                __hip_atomic_store(&wcnt[PAR], 0u,                               \
                                __ATOMIC_RELAXED, __HIP_MEMORY_SCOPE_WORKGROUP); \
                unsigned ep_ = (EPOCH);                                          \
                asm volatile("global_store_dword %0, %1, off sc0 sc1"            \
                             :: "v"(fq), "v"(ep_) : "memory");                   \
            }                                                                    \
        }                                                                        \
    } while (0)

    // ================= layer 0 : K = 576 = [x_t(64) | h0(512)] =================
    for (int t = 0; t < TSEQ; ++t) {
        u32x4 xr;
        const bool havex = (kq < 2);
        if (havex) {   // x fragment, issued before poll (plain cached, retired by poll exit)
            const char* xaddr = x16 + (size_t)t*8192 + (bg*16 + l15)*128 + kq*64 + lhi*16;
            asm volatile("global_load_dwordx4 %0, %1, off" : "=v"(xr) : "v"(xaddr) : "memory");
        }
        f32x4 acc[4] = {{0.f,0.f,0.f,0.f},{0.f,0.f,0.f,0.f},{0.f,0.f,0.f,0.f},{0.f,0.f,0.f,0.f}};
        if (t > 0) {
            POLL((unsigned)t);
            const char* hb = y0 + ((size_t)(t-1)*4 + bg)*16384 + base_off;
            u32x4 h0, h1, h2, h3;
            asm volatile("global_load_dwordx4 %0, %4, off\n\t"
                         "global_load_dwordx4 %1, %5, off\n\t"
                         "global_load_dwordx4 %2, %6, off\n\t"
                         "global_load_dwordx4 %3, %7, off"
                         : "=&v"(h0), "=&v"(h1), "=&v"(h2), "=&v"(h3)
                         : "v"(hb), "v"(hb+1024), "v"(hb+2048), "v"(hb+3072) : "memory");
            if (havex) {
                asm volatile("" : "+v"(xr));    // ordered after poll; xr retired at poll exit
                #pragma unroll
                for (int m = 0; m < 4; ++m) acc[m] = mfma16(A[m][4], asb(xr), acc[m]);
            }
            asm volatile("s_waitcnt vmcnt(0)"
                         : "+v"(h0), "+v"(h1), "+v"(h2), "+v"(h3) :: "memory");
            asm volatile("" :: "v"(pf0), "v"(pf1));   // poll stragglers landed; release
            #pragma unroll
            for (int m = 0; m < 4; ++m) acc[m] = mfma16(A[m][0], asb(h0), acc[m]);
            #pragma unroll
            for (int m = 0; m < 4; ++m) acc[m] = mfma16(A[m][1], asb(h1), acc[m]);
            #pragma unroll
            for (int m = 0; m < 4; ++m) acc[m] = mfma16(A[m][2], asb(h2), acc[m]);
            #pragma unroll
            for (int m = 0; m < 4; ++m) acc[m] = mfma16(A[m][3], asb(h3), acc[m]);
        } else if (havex) {
            asm volatile("s_waitcnt vmcnt(0)" : "+v"(xr) :: "memory");
            #pragma unroll
            for (int m = 0; m < 4; ++m) acc[m] = mfma16(A[m][4], asb(xr), acc[m]);
        }
        GSUM_WRITE(t & 1);
        __syncthreads();
        ACT_TAIL(y0 + ((size_t)t*4 + bg)*16384 + hg*512, (unsigned)(t + 1), (t & 1));
    }

    __syncthreads();   // protect bias_l reload vs slow siblings' ACT reads
    {   // ---- reload A + bias for layer 1 (K = 1024 = [y0(512) | h1(512)]) ----
        const char* w1p = ws + OFF_W1;
        #pragma unroll
        for (int m = 0; m < 4; ++m) {
            const char* base = w1p + (size_t)(m*512 + hg*16 + l15)*2048 + lhi*16;
            #pragma unroll
            for (int kk = 0; kk < 4; ++kk) {
                A[m][kk]     = *(const us8v*)(base + (kq*4 + kk)*64);        // y0 k-tiles
                A[m][kk + 4] = *(const us8v*)(base + (16 + kq*4 + kk)*64);   // h  k-tiles
            }
        }
    }
    if (tid < 64) bias_l[tid] = bias[2048 + (tid >> 4)*512 + hg*16 + (tid & 15)];
    __syncthreads();
    // cst carries over: layer1 initial c = layer0 final c (reference quirk)

    for (int t = 0; t < TSEQ; ++t) {
        // y0[t] fragments: issued before poll; retired by the poll's vmcnt waits.
        const char* yb = y0 + ((size_t)t*4 + bg)*16384 + base_off;
        u32x4 yr0, yr1, yr2, yr3;
        asm volatile("global_load_dwordx4 %0, %4, off\n\t"
                     "global_load_dwordx4 %1, %5, off\n\t"
                     "global_load_dwordx4 %2, %6, off\n\t"
                     "global_load_dwordx4 %3, %7, off"
                     : "=&v"(yr0), "=&v"(yr1), "=&v"(yr2), "=&v"(yr3)
                     : "v"(yb), "v"(yb+1024), "v"(yb+2048), "v"(yb+3072) : "memory");

        POLL((unsigned)(512 + t));

        // h1 fragments (ring reused -> bypass caches); latency hides under y0 MFMAs
        const char* rb = ((t == 0) ? (y0 + ((size_t)511*4 + bg)*16384)
                                   : (ring + ((size_t)((t-1) & 1)*4 + bg)*16384)) + base_off;
        u32x4 r0, r1, r2, r3;
        asm volatile("global_load_dwordx4 %0, %4, off sc0 sc1\n\t"
                     "global_load_dwordx4 %1, %5, off sc0 sc1\n\t"
                     "global_load_dwordx4 %2, %6, off sc0 sc1\n\t"
                     "global_load_dwordx4 %3, %7, off sc0 sc1"
                     : "=&v"(r0), "=&v"(r1), "=&v"(r2), "=&v"(r3)
                     : "v"(rb), "v"(rb+1024), "v"(rb+2048), "v"(rb+3072) : "memory");

        asm volatile("" : "+v"(yr0), "+v"(yr1), "+v"(yr2), "+v"(yr3));  // after poll; retired
        f32x4 acc[4] = {{0.f,0.f,0.f,0.f},{0.f,0.f,0.f,0.f},{0.f,0.f,0.f,0.f},{0.f,0.f,0.f,0.f}};
        #pragma unroll
        for (int m = 0; m < 4; ++m) acc[m] = mfma16(A[m][0], asb(yr0), acc[m]);
        #pragma unroll
        for (int m = 0; m < 4; ++m) acc[m] = mfma16(A[m][1], asb(yr1), acc[m]);
        #pragma unroll
        for (int m = 0; m < 4; ++m) acc[m] = mfma16(A[m][2], asb(yr2), acc[m]);
        #pragma unroll
        for (int m = 0; m < 4; ++m) acc[m] = mfma16(A[m][3], asb(yr3), acc[m]);

        asm volatile("s_waitcnt vmcnt(0)"
                     : "+v"(r0), "+v"(r1), "+v"(r2), "+v"(r3) :: "memory");
        asm volatile("" :: "v"(pf0), "v"(pf1));
        #pragma unroll
        for (int m = 0; m < 4; ++m) acc[m] = mfma16(A[m][4], asb(r0), acc[m]);
        #pragma unroll
        for (int m = 0; m < 4; ++m) acc[m] = mfma16(A[m][5], asb(r1), acc[m]);
        #pragma unroll
        for (int m = 0; m < 4; ++m) acc[m] = mfma16(A[m][6], asb(r2), acc[m]);
        #pragma unroll
        for (int m = 0; m < 4; ++m) acc[m] = mfma16(A[m][7], asb(r3), acc[m]);

        GSUM_WRITE(t & 1);
        __syncthreads();
        ACT_TAIL(ring + ((size_t)(t & 1)*4 + bg)*16384 + hg*512, (unsigned)(513 + t), (t & 1));
    }
#undef POLL
#undef GSUM_WRITE
#undef ACT_TAIL
}

// ---------------- final projection: out = h1_final @ lin_w.T + lin_b ----------------
__global__ void final_linear(const char* __restrict__ ws,
                             const float* __restrict__ linw, const float* __restrict__ linb,
                             float* __restrict__ out)
{
    __shared__ float hrow[512];
    int b = blockIdx.x;        // global batch 0..63
    int o = threadIdx.x;       // 64 outputs
    int bg = b >> 4, bl = b & 15;
    // t=511 -> ring parity 1; xch layout [par][bg][hg][b][p]
    const char* src = ws + OFF_RING + ((size_t)(4 + bg))*16384
                         + (o >> 1)*512 + bl*32 + (o & 1)*16;
    {
        us8v v = *(const us8v*)src;
        #pragma unroll
        for (int p = 0; p < 8; ++p)
            hrow[o*8+p] = __builtin_bit_cast(float, ((unsigned)v[p]) << 16);
    }
    __syncthreads();
    float acc = linb[o];
    const float* wrow = linw + o*512;
    #pragma unroll 8
    for (int k = 0; k < 512; ++k) acc += hrow[k] * wrow[k];
    out[b*64 + o] = acc;
}

extern "C" void kernel_launch(void* const* d_in, const int* in_sizes, int n_in,
                              void* d_out, int out_size, void* d_ws, size_t ws_size,
                              hipStream_t stream)
{
    const float* x    = (const float*)d_in[0];
    const float* wih0 = (const float*)d_in[1];
    const float* whh0 = (const float*)d_in[2];
    const float* bih0 = (const float*)d_in[3];
    const float* bhh0 = (const float*)d_in[4];
    const float* wih1 = (const float*)d_in[5];
    const float* whh1 = (const float*)d_in[6];
    const float* bih1 = (const float*)d_in[7];
    const float* bhh1 = (const float*)d_in[8];
    const float* linw = (const float*)d_in[9];
    const float* linb = (const float*)d_in[10];
    char* ws = (char*)d_ws;

    // zero epoch flags (visible to lstm_persist via dispatch-boundary ordering)
    (void)hipMemsetAsync(ws + OFF_FLAGS, 0, 16384, stream);
    hipLaunchKernelGGL(setup_kernel, dim3(1024), dim3(256), 0, stream,
                       x, wih0, whh0, bih0, bhh0, wih1, whh1, bih1, bhh1, ws);
    hipLaunchKernelGGL(lstm_persist, dim3(128), dim3(256), 0, stream, ws);
    hipLaunchKernelGGL(final_linear, dim3(64), dim3(64), 0, stream,
                       ws, linw, linb, (float*)d_out);
}